// Round 4
// baseline (417.248 us; speedup 1.0000x reference)
//
#include <hip/hip_runtime.h>

#define N_BONDS 50000
#define N_EDGES 600000
#define R_BONDS 8
#define BONDS_PER_BLOCK 32   // 4 waves * 8 bonds

typedef float f4 __attribute__((ext_vector_type(4)));

__device__ __forceinline__ float bcastf(float v, int l) {
    return __builtin_bit_cast(float, __builtin_amdgcn_readlane(__builtin_bit_cast(int, v), l));
}
__device__ __forceinline__ int bcasti(int v, int l) {
    return __builtin_amdgcn_readlane(v, l);
}
__device__ __forceinline__ f4 f4zero() { return (f4){0.f, 0.f, 0.f, 0.f}; }
__device__ __forceinline__ void fma4(f4& a, float s, const f4& b) {
    a.x = fmaf(s, b.x, a.x); a.y = fmaf(s, b.y, a.y);
    a.z = fmaf(s, b.z, a.z); a.w = fmaf(s, b.w, a.w);
}

__global__ __launch_bounds__(256, 4)
void fused_gather_segsum_mm(const float* __restrict__ bond,   // [N_BONDS][64]
                            const float* __restrict__ sph,    // [N_EDGES][64]
                            const int*   __restrict__ edges,  // [N_EDGES][2]
                            const float* __restrict__ Kmat,   // [128][64]
                            const float* __restrict__ bias,   // [64]
                            float* __restrict__ out)          // [N_BONDS][64]
{
    __shared__ f4 ldsK[128 * 16];   // 32 KB, K as f4[128][16]
    const int tid  = threadIdx.x;
    const int lane = tid & 63;
    const int wid  = tid >> 6;
    const int fl   = lane & 15;   // float4-column within row
    const int sg   = lane >> 4;   // edge-subgroup within quad

    {   // stage K (coalesced 16B)
        const f4* K4 = (const f4*)Kmat;
        #pragma unroll
        for (int i = 0; i < 8; ++i)
            ldsK[tid + i * 256] = K4[tid + i * 256];
    }
    __syncthreads();

    const int b0 = blockIdx.x * BONDS_PER_BLOCK + wid * R_BONDS;
    if (b0 >= N_BONDS) return;
    int b_end = b0 + R_BONDS; if (b_end > N_BONDS) b_end = N_BONDS;

    const f4*   bond4  = (const f4*)bond;
    const f4*   sph4   = (const f4*)sph;
    const int2* edges2 = (const int2*)edges;
    f4*         out4   = (f4*)out;
    const f4    bias4  = ((const f4*)bias)[fl];
    const bool  storer = (sg == 0);

    auto lower_bound = [&](int target) -> int {
        int lo = 0, hi = N_EDGES;
        while (lo < hi) {
            int mid = (lo + hi) >> 1;
            if (edges[mid * 2] < target) lo = mid + 1; else hi = mid;
        }
        return lo;
    };
    const int e_lo = lower_bound(b0);
    const int e_hi = lower_bound(b_end);

    f4 accG = f4zero(), accS = f4zero();
    int b = b0;

    // cross-subgroup reduce (subgroups hold partial sums of same features)
    auto xr = [&](f4 v) -> f4 {
        v.x += __shfl_xor(v.x, 16); v.y += __shfl_xor(v.y, 16);
        v.z += __shfl_xor(v.z, 16); v.w += __shfl_xor(v.w, 16);
        v.x += __shfl_xor(v.x, 32); v.y += __shfl_xor(v.y, 32);
        v.z += __shfl_xor(v.z, 32); v.w += __shfl_xor(v.w, 32);
        return v;
    };

    auto flush = [&](int bb, f4 aGin, f4 aSin) {
        f4 aG = xr(aGin), aS = xr(aSin);
        f4 o = bias4;
        #pragma unroll
        for (int d = 0; d < 64; ++d) {
            float g, s;
            if ((d & 3) == 0)      { g = aG.x; s = aS.x; }
            else if ((d & 3) == 1) { g = aG.y; s = aS.y; }
            else if ((d & 3) == 2) { g = aG.z; s = aS.z; }
            else                   { g = aG.w; s = aS.w; }
            const float gb = bcastf(g, d >> 2);
            const float sb = bcastf(s, d >> 2);
            const f4 kt = ldsK[d * 16 + fl];
            const f4 kb = ldsK[(64 + d) * 16 + fl];
            o.x = fmaf(gb, kt.x, o.x); o.y = fmaf(gb, kt.y, o.y);
            o.z = fmaf(gb, kt.z, o.z); o.w = fmaf(gb, kt.w, o.w);
            o.x = fmaf(sb, kb.x, o.x); o.y = fmaf(sb, kb.y, o.y);
            o.z = fmaf(sb, kb.z, o.z); o.w = fmaf(sb, kb.w, o.w);
        }
        if (storer) __builtin_nontemporal_store(o, &out4[bb * 16 + fl]);
    };
    auto empty_row = [&](int bb) {
        if (storer) __builtin_nontemporal_store(bias4, &out4[bb * 16 + fl]);
    };

    int e = e_lo;
    const bool any_edges = (e_lo < e_hi);
    while (e < e_hi) {
        const int wlen = (e_hi - e < 64) ? (e_hi - e) : 64;
        int2 p = make_int2(0, 0);
        if (lane < wlen) p = edges2[e + lane];   // 64 edge indices, coalesced

        f4 pvA[4], svA[4], pvB[4], svB[4];

        auto issue = [&](int g, f4* pv, f4* sv) {
            #pragma unroll
            for (int q = 0; q < 4; ++q) {
                const int c = g * 16 + q * 4;
                if (c < wlen) {
                    const int src  = c + sg;                // edge-in-window for my subgroup
                    const int nbr  = __shfl(p.y, src);      // 0 if src >= wlen (p zeroed)
                    const int eidx = (src < wlen) ? src : 0;
                    pv[q] = bond4[nbr * 16 + fl];
                    sv[q] = __builtin_nontemporal_load(&sph4[(e + eidx) * 16 + fl]);
                } else { pv[q] = f4zero(); sv[q] = f4zero(); }
            }
        };

        auto process = [&](int g, f4* pv, f4* sv) {
            #pragma unroll
            for (int q = 0; q < 4; ++q) {
                const int c = g * 16 + q * 4;
                if (c < wlen) {
                    const int m = (wlen - c < 4) ? (wlen - c) : 4;
                    const int s_first = bcasti(p.x, c);
                    const int s_last  = bcasti(p.x, c + 3);
                    if (m == 4 && s_first == b && s_last == b) {
                        // whole quad in open segment
                        accG += pv[q]; accS += sv[q];
                    } else {
                        #pragma unroll 1
                        for (int j = 0; j < m; ++j) {           // wave-uniform serial path
                            const int se = bcasti(p.x, c + j);
                            if (se != b) {
                                flush(b, accG, accS);
                                for (int bb = b + 1; bb < se; ++bb) empty_row(bb);
                                b = se; accG = f4zero(); accS = f4zero();
                            }
                            const float sel = (sg == j) ? 1.0f : 0.0f;
                            fma4(accG, sel, pv[q]);
                            fma4(accS, sel, sv[q]);
                        }
                    }
                }
            }
        };

        const int ng = (wlen + 15) >> 4;
        issue(0, pvA, svA);
        for (int g = 0; g < ng; g += 2) {
            if (g + 1 < ng) issue(g + 1, pvB, svB);
            process(g, pvA, svA);
            if (g + 1 < ng) {
                if (g + 2 < ng) issue(g + 2, pvA, svA);
                process(g + 1, pvB, svB);
            }
        }
        e += wlen;
    }

    if (any_edges) {
        flush(b, accG, accS);
        for (int bb = b + 1; bb < b_end; ++bb) empty_row(bb);
    } else {
        for (int bb = b0; bb < b_end; ++bb) empty_row(bb);
    }
}

extern "C" void kernel_launch(void* const* d_in, const int* in_sizes, int n_in,
                              void* d_out, int out_size, void* d_ws, size_t ws_size,
                              hipStream_t stream) {
    const float* bond  = (const float*)d_in[0];
    const float* sph   = (const float*)d_in[1];
    const int*   edges = (const int*)d_in[2];
    const float* Kmat  = (const float*)d_in[3];
    const float* bias  = (const float*)d_in[4];
    float* out = (float*)d_out;

    const int nblocks = (N_BONDS + BONDS_PER_BLOCK - 1) / BONDS_PER_BLOCK;
    fused_gather_segsum_mm<<<nblocks, 256, 0, stream>>>(bond, sph, edges, Kmat, bias, out);
}

// Round 5
// 88.742 us; speedup vs baseline: 4.7018x; 4.7018x over previous
//
#include <hip/hip_runtime.h>

#define N_BONDS 50000
#define N_EDGES 600000
#define R_BONDS 8
#define WAVES_PER_BLOCK 4
#define BONDS_PER_BLOCK (R_BONDS * WAVES_PER_BLOCK)   // 32

typedef float f4 __attribute__((ext_vector_type(4)));

__device__ __forceinline__ float bcastf(float v, int l) {
    return __builtin_bit_cast(float, __builtin_amdgcn_readlane(__builtin_bit_cast(int, v), l));
}

// ---------------- kernel 1: starts[b] = lower_bound(seg, b), b in [0, N_BONDS] ----
__global__ __launch_bounds__(256)
void fill_starts(const int* __restrict__ edges, int* __restrict__ starts) {
    const int e = blockIdx.x * blockDim.x + threadIdx.x;
    if (e >= N_EDGES) return;
    const int2* edges2 = (const int2*)edges;
    const int s  = edges2[e].x;
    const int sp = (e == 0) ? -1 : edges2[e - 1].x;
    for (int b = sp + 1; b <= s; ++b) starts[b] = e;        // disjoint ranges, full cover
    if (e == N_EDGES - 1)
        for (int b = s + 1; b <= N_BONDS; ++b) starts[b] = N_EDGES;
}

// ---------------- kernel 2: fused gather + segsum + matvec ------------------------
__global__ __launch_bounds__(256, 6)
void fused_gather_segsum_mm(const float* __restrict__ bond,   // [N_BONDS][64]
                            const float* __restrict__ sph,    // [N_EDGES][64]
                            const int*   __restrict__ edges,  // [N_EDGES][2]
                            const float* __restrict__ Kmat,   // [128][64]
                            const float* __restrict__ bias,   // [64]
                            const int*   __restrict__ starts, // [N_BONDS+1]
                            float* __restrict__ out)          // [N_BONDS][64]
{
    __shared__ float ldsK[128 * 64];   // 32 KB
    const int tid  = threadIdx.x;
    const int lane = tid & 63;
    const int wid  = tid >> 6;

    {   // stage K, coalesced 16B
        const f4* K4 = (const f4*)Kmat;
        f4*       L4 = (f4*)ldsK;
        #pragma unroll
        for (int i = 0; i < 8; ++i) L4[tid + i * 256] = K4[tid + i * 256];
    }
    __syncthreads();                                   // the only barrier

    const int b0 = blockIdx.x * BONDS_PER_BLOCK + wid * R_BONDS;
    if (b0 >= N_BONDS) return;

    // prefetch all 9 segment boundaries into SGPRs (consecutive -> merged s_loads)
    int st[R_BONDS + 1];
    #pragma unroll
    for (int r = 0; r <= R_BONDS; ++r)
        st[r] = __builtin_amdgcn_readfirstlane(starts[b0 + r]);

    float slotG[R_BONDS], slotS[R_BONDS];

    #pragma unroll
    for (int r = 0; r < R_BONDS; ++r) {
        float aG = 0.f, aS = 0.f;
        int e = st[r];
        const int t = st[r + 1];

        // 4-edge groups: 8 independent loads in flight, scalar index loads
        for (; e + 4 <= t; e += 4) {
            const int n0 = edges[2 * e + 1];
            const int n1 = edges[2 * e + 3];
            const int n2 = edges[2 * e + 5];
            const int n3 = edges[2 * e + 7];
            const float g0 = bond[n0 * 64 + lane];
            const float g1 = bond[n1 * 64 + lane];
            const float g2 = bond[n2 * 64 + lane];
            const float g3 = bond[n3 * 64 + lane];
            const float s0 = __builtin_nontemporal_load(&sph[(e + 0) * 64 + lane]);
            const float s1 = __builtin_nontemporal_load(&sph[(e + 1) * 64 + lane]);
            const float s2 = __builtin_nontemporal_load(&sph[(e + 2) * 64 + lane]);
            const float s3 = __builtin_nontemporal_load(&sph[(e + 3) * 64 + lane]);
            aG += (g0 + g1) + (g2 + g3);
            aS += (s0 + s1) + (s2 + s3);
        }
        for (; e < t; ++e) {                           // tail (<=3)
            const int n = edges[2 * e + 1];
            aG += bond[n * 64 + lane];
            aS += __builtin_nontemporal_load(&sph[e * 64 + lane]);
        }
        slotG[r] = aG;
        slotS[r] = aS;
    }

    // deferred matvec: 8 bonds amortize each LDS K read
    float acc[R_BONDS];
    const float bl = bias[lane];
    #pragma unroll
    for (int r = 0; r < R_BONDS; ++r) acc[r] = bl;

    #pragma unroll 2
    for (int d = 0; d < 64; ++d) {                     // d uniform -> readlane(s-index)
        const float kt = ldsK[d * 64 + lane];          // 2-way bank alias: free
        const float kb = ldsK[(64 + d) * 64 + lane];
        #pragma unroll
        for (int r = 0; r < R_BONDS; ++r) {
            acc[r] = fmaf(bcastf(slotG[r], d), kt, acc[r]);
            acc[r] = fmaf(bcastf(slotS[r], d), kb, acc[r]);
        }
    }

    #pragma unroll
    for (int r = 0; r < R_BONDS; ++r)
        if (b0 + r < N_BONDS)
            __builtin_nontemporal_store(acc[r], &out[(b0 + r) * 64 + lane]);
}

extern "C" void kernel_launch(void* const* d_in, const int* in_sizes, int n_in,
                              void* d_out, int out_size, void* d_ws, size_t ws_size,
                              hipStream_t stream) {
    const float* bond  = (const float*)d_in[0];
    const float* sph   = (const float*)d_in[1];
    const int*   edges = (const int*)d_in[2];
    const float* Kmat  = (const float*)d_in[3];
    const float* bias  = (const float*)d_in[4];
    float* out   = (float*)d_out;
    int* starts  = (int*)d_ws;                         // (N_BONDS+1)*4 = 200 KB

    fill_starts<<<(N_EDGES + 255) / 256, 256, 0, stream>>>(edges, starts);

    const int nblocks = (N_BONDS + BONDS_PER_BLOCK - 1) / BONDS_PER_BLOCK;
    fused_gather_segsum_mm<<<nblocks, 256, 0, stream>>>(bond, sph, edges, Kmat,
                                                        bias, starts, out);
}

// Round 6
// 79.595 us; speedup vs baseline: 5.2421x; 1.1149x over previous
//
#include <hip/hip_runtime.h>

#define N_BONDS 50000
#define N_EDGES 600000
#define R_BONDS 8
#define BONDS_PER_BLOCK 32   // 4 waves * 8 bonds

typedef float f4 __attribute__((ext_vector_type(4)));

__device__ __forceinline__ float bcastf(float v, int l) {
    return __builtin_bit_cast(float, __builtin_amdgcn_readlane(__builtin_bit_cast(int, v), l));
}
__device__ __forceinline__ f4 f4zero() { return (f4){0.f, 0.f, 0.f, 0.f}; }
__device__ __forceinline__ void fma4(f4& a, float s, const f4& b) {
    a.x = fmaf(s, b.x, a.x); a.y = fmaf(s, b.y, a.y);
    a.z = fmaf(s, b.z, a.z); a.w = fmaf(s, b.w, a.w);
}

// ---- kernel 1: starts[b] = lower_bound(seg, b), b in [0, N_BONDS] ----
__global__ __launch_bounds__(256)
void fill_starts(const int* __restrict__ edges, int* __restrict__ starts) {
    const int e = blockIdx.x * blockDim.x + threadIdx.x;
    if (e >= N_EDGES) return;
    const int2* edges2 = (const int2*)edges;
    const int s  = edges2[e].x;
    const int sp = (e == 0) ? -1 : edges2[e - 1].x;
    for (int b = sp + 1; b <= s; ++b) starts[b] = e;
    if (e == N_EDGES - 1)
        for (int b = s + 1; b <= N_BONDS; ++b) starts[b] = N_EDGES;
}

// ---- kernel 2: fused gather + segsum + matvec ----
__global__ __launch_bounds__(256, 4)
void fused_gather_segsum_mm(const float* __restrict__ bond,   // [N_BONDS][64]
                            const float* __restrict__ sph,    // [N_EDGES][64]
                            const int*   __restrict__ edges,  // [N_EDGES][2]
                            const float* __restrict__ Kmat,   // [128][64]
                            const float* __restrict__ bias,   // [64]
                            const int*   __restrict__ starts, // [N_BONDS+1]
                            float* __restrict__ out)          // [N_BONDS][64]
{
    __shared__ float ldsK[128 * 64];   // 32 KB
    const int tid  = threadIdx.x;
    const int lane = tid & 63;
    const int wid  = tid >> 6;
    const int fl   = lane & 15;
    const int sg   = lane >> 4;

    {   // stage K, coalesced 16B
        const f4* K4 = (const f4*)Kmat;
        f4*       L4 = (f4*)ldsK;
        #pragma unroll
        for (int i = 0; i < 8; ++i) L4[tid + i * 256] = K4[tid + i * 256];
    }
    __syncthreads();                                   // only barrier

    const int b0 = blockIdx.x * BONDS_PER_BLOCK + wid * R_BONDS;
    if (b0 >= N_BONDS) return;

    int st[R_BONDS + 1];                               // compile-time indexed only
    #pragma unroll
    for (int r = 0; r <= R_BONDS; ++r)
        st[r] = __builtin_amdgcn_readfirstlane(starts[b0 + r]);

    const int eb    = st[0];
    const int total = st[R_BONDS] - eb;

    const f4*   bond4  = (const f4*)bond;
    const f4*   sph4   = (const f4*)sph;
    const int2* edges2 = (const int2*)edges;

    float slotG[R_BONDS], slotS[R_BONDS];              // scalar layout: lane = feature
    f4 aG = f4zero(), aS = f4zero();
    int r = 0, cs = 0, bnd = st[1] - eb;

    // cross-subgroup reduce + transpose f4 layout -> scalar layout (lane d = feat d)
    auto txr = [&](f4 v) -> float {
        v.x += __shfl_xor(v.x, 16); v.y += __shfl_xor(v.y, 16);
        v.z += __shfl_xor(v.z, 16); v.w += __shfl_xor(v.w, 16);
        v.x += __shfl_xor(v.x, 32); v.y += __shfl_xor(v.y, 32);
        v.z += __shfl_xor(v.z, 32); v.w += __shfl_xor(v.w, 32);
        const int src = lane >> 2;
        const float s0 = __shfl(v.x, src), s1 = __shfl(v.y, src);
        const float s2 = __shfl(v.z, src), s3 = __shfl(v.w, src);
        const float r01 = (lane & 1) ? s1 : s0;
        const float r23 = (lane & 1) ? s3 : s2;
        return (lane & 2) ? r23 : r01;
    };

    // boundary-group path: masked add, close bonds that end inside this group
    auto slowpath = [&](int q, f4 GV, f4 SV) {
        const int qe = q + sg;
        while (true) {
            const float m = (qe >= cs && qe < bnd) ? 1.f : 0.f;
            fma4(aG, m, GV); fma4(aS, m, SV);
            if (bnd > q + 4) break;                    // bond continues past group
            const float tG = txr(aG), tS = txr(aS);    // close bond r
            #pragma unroll
            for (int rr = 0; rr < R_BONDS; ++rr)
                if (rr == r) { slotG[rr] = tG; slotS[rr] = tS; }
            aG = f4zero(); aS = f4zero();
            cs = bnd;
            ++r;
            if (r >= R_BONDS) { bnd = 0x7fffffff; break; }
            #pragma unroll
            for (int rr = 2; rr <= R_BONDS; ++rr)
                if (r + 1 == rr) bnd = st[rr] - eb;
        }
    };

    int w0 = 0;
    while (w0 < total) {
        int wlen = total - w0; if (wlen > 64) wlen = 64;
        int2 p = make_int2(0, 0);
        if (lane < wlen) p = edges2[eb + w0 + lane];   // 64 edge indices, coalesced
        const int ng = (wlen + 3) >> 2;

        for (int c = 0; c < ng; c += 4) {
            f4 g0, g1, g2, g3, s0, s1, s2, s3;

#define ISSUE(GG, GV, SV) do { \
            if ((c + GG) < ng) { \
                const int idx_ = (c + GG) * 4 + sg; \
                const int nbr_ = __shfl(p.y, idx_); \
                int qe_ = w0 + idx_; if (qe_ >= total) qe_ = total - 1; \
                GV = bond4[nbr_ * 16 + fl]; \
                SV = __builtin_nontemporal_load(&sph4[(eb + qe_) * 16 + fl]); \
            } else { GV = f4zero(); SV = f4zero(); } } while (0)

            ISSUE(0, g0, s0); ISSUE(1, g1, s1); ISSUE(2, g2, s2); ISSUE(3, g3, s3);
#undef ISSUE

#define ACCG(GG, GV, SV) do { \
            if ((c + GG) < ng) { \
                const int q_ = w0 + (c + GG) * 4; \
                if (q_ + 4 <= bnd) { aG += GV; aS += SV; } \
                else slowpath(q_, GV, SV); \
            } } while (0)

            ACCG(0, g0, s0); ACCG(1, g1, s1); ACCG(2, g2, s2); ACCG(3, g3, s3);
#undef ACCG
        }
        w0 += wlen;
    }

    {   // close remaining open/empty bonds
        const float tG = txr(aG), tS = txr(aS);
        #pragma unroll
        for (int rr = 0; rr < R_BONDS; ++rr) {
            if (rr == r)     { slotG[rr] = tG;  slotS[rr] = tS; }
            else if (rr > r) { slotG[rr] = 0.f; slotS[rr] = 0.f; }
        }
    }

    // ---- deferred matvec: 8 bonds amortize each LDS K read (R5-proven) ----
    float acc[R_BONDS];
    const float bl = bias[lane];
    #pragma unroll
    for (int rr = 0; rr < R_BONDS; ++rr) acc[rr] = bl;

    #pragma unroll 2
    for (int d = 0; d < 64; ++d) {
        const float kt = ldsK[d * 64 + lane];
        const float kb = ldsK[(64 + d) * 64 + lane];
        #pragma unroll
        for (int rr = 0; rr < R_BONDS; ++rr) {
            acc[rr] = fmaf(bcastf(slotG[rr], d), kt, acc[rr]);
            acc[rr] = fmaf(bcastf(slotS[rr], d), kb, acc[rr]);
        }
    }

    #pragma unroll
    for (int rr = 0; rr < R_BONDS; ++rr)
        if (b0 + rr < N_BONDS)
            __builtin_nontemporal_store(acc[rr], &out[(b0 + rr) * 64 + lane]);
}

extern "C" void kernel_launch(void* const* d_in, const int* in_sizes, int n_in,
                              void* d_out, int out_size, void* d_ws, size_t ws_size,
                              hipStream_t stream) {
    const float* bond  = (const float*)d_in[0];
    const float* sph   = (const float*)d_in[1];
    const int*   edges = (const int*)d_in[2];
    const float* Kmat  = (const float*)d_in[3];
    const float* bias  = (const float*)d_in[4];
    float* out  = (float*)d_out;
    int* starts = (int*)d_ws;                          // (N_BONDS+1)*4 = 200 KB

    fill_starts<<<(N_EDGES + 255) / 256, 256, 0, stream>>>(edges, starts);

    const int nblocks = (N_BONDS + BONDS_PER_BLOCK - 1) / BONDS_PER_BLOCK;
    fused_gather_segsum_mm<<<nblocks, 256, 0, stream>>>(bond, sph, edges, Kmat,
                                                        bias, starts, out);
}

// Round 7
// 77.724 us; speedup vs baseline: 5.3684x; 1.0241x over previous
//
#include <hip/hip_runtime.h>

#define N_BONDS 50000
#define N_EDGES 600000
#define R_BONDS 4
#define THREADS 512
#define BONDS_PER_BLOCK 32   // 8 waves * 4 bonds

typedef float f4 __attribute__((ext_vector_type(4)));

__device__ __forceinline__ float bcastf(float v, int l) {
    return __builtin_bit_cast(float, __builtin_amdgcn_readlane(__builtin_bit_cast(int, v), l));
}
__device__ __forceinline__ f4 f4zero() { return (f4){0.f, 0.f, 0.f, 0.f}; }
__device__ __forceinline__ void fma4(f4& a, float s, const f4& b) {
    a.x = fmaf(s, b.x, a.x); a.y = fmaf(s, b.y, a.y);
    a.z = fmaf(s, b.z, a.z); a.w = fmaf(s, b.w, a.w);
}

// ---- kernel 1: starts[b] = lower_bound(seg, b), b in [0, N_BONDS] ----
__global__ __launch_bounds__(256)
void fill_starts(const int* __restrict__ edges, int* __restrict__ starts) {
    const int e = blockIdx.x * blockDim.x + threadIdx.x;
    if (e >= N_EDGES) return;
    const int2* edges2 = (const int2*)edges;
    const int s  = edges2[e].x;
    const int sp = (e == 0) ? -1 : edges2[e - 1].x;
    for (int b = sp + 1; b <= s; ++b) starts[b] = e;
    if (e == N_EDGES - 1)
        for (int b = s + 1; b <= N_BONDS; ++b) starts[b] = N_EDGES;
}

// ---- kernel 2: fused gather + segsum + matvec ----
__global__ __launch_bounds__(THREADS, 8)
void fused_gather_segsum_mm(const float* __restrict__ bond,   // [N_BONDS][64]
                            const float* __restrict__ sph,    // [N_EDGES][64]
                            const int*   __restrict__ edges,  // [N_EDGES][2]
                            const float* __restrict__ Kmat,   // [128][64]
                            const float* __restrict__ bias,   // [64]
                            const int*   __restrict__ starts, // [N_BONDS+1]
                            float* __restrict__ out)          // [N_BONDS][64]
{
    __shared__ float ldsK[128 * 64];   // 32 KB shared by 8 waves
    const int tid  = threadIdx.x;
    const int lane = tid & 63;
    const int wid  = tid >> 6;
    const int fl   = lane & 15;   // f4-column within a 64-float row
    const int sg   = lane >> 4;   // subgroup = edge-within-quad

    {   // stage K, coalesced 16B (2048 f4 / 512 threads = 4 each)
        const f4* K4 = (const f4*)Kmat;
        f4*       L4 = (f4*)ldsK;
        #pragma unroll
        for (int i = 0; i < 4; ++i) L4[tid + i * THREADS] = K4[tid + i * THREADS];
    }
    __syncthreads();                                   // only barrier

    const int b0 = blockIdx.x * BONDS_PER_BLOCK + wid * R_BONDS;
    if (b0 >= N_BONDS) return;

    int st[R_BONDS + 1];                               // SGPR, static-indexed only
    #pragma unroll
    for (int r = 0; r <= R_BONDS; ++r)
        st[r] = __builtin_amdgcn_readfirstlane(starts[b0 + r]);

    const f4* bond4 = (const f4*)bond;
    const f4* sph4  = (const f4*)sph;

    // cross-subgroup reduce + transpose f4 layout -> scalar layout (lane d = feat d)
    auto txr = [&](f4 v) -> float {
        v.x += __shfl_xor(v.x, 16); v.y += __shfl_xor(v.y, 16);
        v.z += __shfl_xor(v.z, 16); v.w += __shfl_xor(v.w, 16);
        v.x += __shfl_xor(v.x, 32); v.y += __shfl_xor(v.y, 32);
        v.z += __shfl_xor(v.z, 32); v.w += __shfl_xor(v.w, 32);
        const int src = lane >> 2;
        const float s0 = __shfl(v.x, src), s1 = __shfl(v.y, src);
        const float s2 = __shfl(v.z, src), s3 = __shfl(v.w, src);
        const float r01 = (lane & 1) ? s1 : s0;
        const float r23 = (lane & 1) ? s3 : s2;
        return (lane & 2) ? r23 : r01;
    };

    // load one quad (4 edges starting at uniform ea); indices via scalar loads
    auto loadq = [&](int ea, f4& gv, f4& sv) {
        const int e0 = (ea     < N_EDGES) ? ea     : N_EDGES - 1;
        const int e1 = (ea + 1 < N_EDGES) ? ea + 1 : N_EDGES - 1;
        const int e2 = (ea + 2 < N_EDGES) ? ea + 2 : N_EDGES - 1;
        const int e3 = (ea + 3 < N_EDGES) ? ea + 3 : N_EDGES - 1;
        const int n0 = edges[2 * e0 + 1];              // uniform -> s_load
        const int n1 = edges[2 * e1 + 1];
        const int n2 = edges[2 * e2 + 1];
        const int n3 = edges[2 * e3 + 1];
        const int ns = (sg == 0) ? n0 : (sg == 1) ? n1 : (sg == 2) ? n2 : n3;
        const int es = (sg == 0) ? e0 : (sg == 1) ? e1 : (sg == 2) ? e2 : e3;
        gv = bond4[ns * 16 + fl];
        sv = __builtin_nontemporal_load(&sph4[es * 16 + fl]);
    };
    auto accq = [&](int ea, int t, const f4& gv, const f4& sv, f4& aG, f4& aS) {
        const float sel = (ea + sg < t) ? 1.f : 0.f;   // masks partial last quad
        fma4(aG, sel, gv);
        fma4(aS, sel, sv);
    };

    // stream all edges of one bond; 2-deep quad pipeline (named regs, no arrays)
    auto run_bond = [&](int s, int t, float& oG, float& oS) {
        f4 aG = f4zero(), aS = f4zero();
        const int nq = (t - s + 3) >> 2;
        if (nq > 0) {
            f4 gA, sA, gB, sB;
            loadq(s, gA, sA);
            int q = 0;
            for (; q + 2 <= nq; q += 2) {
                loadq(s + 4 * (q + 1), gB, sB);
                accq(s + 4 * q, t, gA, sA, aG, aS);
                if (q + 2 < nq) loadq(s + 4 * (q + 2), gA, sA);
                accq(s + 4 * (q + 1), t, gB, sB, aG, aS);
            }
            if (q < nq) accq(s + 4 * q, t, gA, sA, aG, aS);
        }
        oG = txr(aG);
        oS = txr(aS);
    };

    float slotG[R_BONDS], slotS[R_BONDS];              // static-indexed only
    run_bond(st[0], st[1], slotG[0], slotS[0]);
    run_bond(st[1], st[2], slotG[1], slotS[1]);
    run_bond(st[2], st[3], slotG[2], slotS[2]);
    run_bond(st[3], st[4], slotG[3], slotS[3]);

    // ---- deferred matvec: 4 bonds amortize each LDS K read ----
    float acc[R_BONDS];
    const float bl = bias[lane];
    #pragma unroll
    for (int r = 0; r < R_BONDS; ++r) acc[r] = bl;

    #pragma unroll 4
    for (int d = 0; d < 64; ++d) {
        const float kt = ldsK[d * 64 + lane];          // 2-way bank alias: free
        const float kb = ldsK[(64 + d) * 64 + lane];
        #pragma unroll
        for (int r = 0; r < R_BONDS; ++r) {
            acc[r] = fmaf(bcastf(slotG[r], d), kt, acc[r]);
            acc[r] = fmaf(bcastf(slotS[r], d), kb, acc[r]);
        }
    }

    #pragma unroll
    for (int r = 0; r < R_BONDS; ++r)
        if (b0 + r < N_BONDS)
            __builtin_nontemporal_store(acc[r], &out[(b0 + r) * 64 + lane]);
}

extern "C" void kernel_launch(void* const* d_in, const int* in_sizes, int n_in,
                              void* d_out, int out_size, void* d_ws, size_t ws_size,
                              hipStream_t stream) {
    const float* bond  = (const float*)d_in[0];
    const float* sph   = (const float*)d_in[1];
    const int*   edges = (const int*)d_in[2];
    const float* Kmat  = (const float*)d_in[3];
    const float* bias  = (const float*)d_in[4];
    float* out  = (float*)d_out;
    int* starts = (int*)d_ws;                          // (N_BONDS+1)*4 = 200 KB

    fill_starts<<<(N_EDGES + 255) / 256, 256, 0, stream>>>(edges, starts);

    const int nblocks = (N_BONDS + BONDS_PER_BLOCK - 1) / BONDS_PER_BLOCK;
    fused_gather_segsum_mm<<<nblocks, THREADS, 0, stream>>>(bond, sph, edges, Kmat,
                                                            bias, starts, out);
}